// Round 8
// baseline (606.251 us; speedup 1.0000x reference)
//
#include <hip/hip_runtime.h>
#include <hip/hip_bf16.h>

// ---------------- constants (match reference) ----------------
#define DIM_IN 1000
#define HEADS 8
#define HID 8
#define DIM_OUT 32
#define NEG_SLOPE 0.2f
#define RESCALE_THR 8.f

typedef __attribute__((ext_vector_type(4))) float f32x4;
typedef __attribute__((ext_vector_type(8))) short s16x8;

__device__ __forceinline__ unsigned bf16rne(float f) {
    unsigned u = __float_as_uint(f);
    return (u + 0x7FFFu + ((u >> 16) & 1u)) >> 16;
}
__device__ __forceinline__ unsigned pack2(float lo, float hi) {
    return bf16rne(lo) | (bf16rne(hi) << 16);
}

// ---------------- W pre-pack: fragment-ordered bf16 [32 kt][8 ctg][64 lane][8] ----
__global__ __launch_bounds__(256) void pack_w(
    const float* __restrict__ W1, const float* __restrict__ W2,
    ushort* __restrict__ wpack)
{
    int t = blockIdx.x * 256 + threadIdx.x;   // 0..16383
    if (t >= 32 * 8 * 64) return;
    int lane = t & 63;
    int ctg = (t >> 6) & 7;
    int kt = t >> 9;
    int c = ctg * 16 + (lane & 15);
    int kbase = kt * 32 + (lane >> 4) * 8;
    ushort v[8] __attribute__((aligned(16)));
#pragma unroll
    for (int j = 0; j < 8; j++) {
        int k = kbase + j;
        float w = 0.f;
        if (k < DIM_IN) w = (c < 64) ? W1[(size_t)k * 64 + c] : W2[(size_t)k * 64 + (c - 64)];
        v[j] = (ushort)bf16rne(w);
    }
    *(uint4*)&wpack[(size_t)t * 8] = *(const uint4*)v;
}

// ---------------- GEMM1 (MFMA bf16): [N,128] = x[N,1000] @ [W1 | W2a] ----------------
__global__ __launch_bounds__(256) void gemm1_mfma(
    const float* __restrict__ x, const ushort* __restrict__ wpack,
    float* __restrict__ hp1, float* __restrict__ p2, int N)
{
    __shared__ __align__(16) ushort a_lds[2][64 * 32];
    const int tid = threadIdx.x;
    const int lane = tid & 63;
    const int wc = tid >> 6;
    const int rowbase = blockIdx.x * 64;

    const int srow = tid >> 2;
    const int skg = tid & 3;
    const int sgr = rowbase + srow;
    const int sidx = ((srow >> 4) * 64 + skg * 16 + (srow & 15)) * 8;

    f32x4 acc[4][2];
#pragma unroll
    for (int i = 0; i < 4; i++)
#pragma unroll
        for (int j = 0; j < 2; j++) acc[i][j] = (f32x4){0.f, 0.f, 0.f, 0.f};

    float4 s0, s1;
    auto load_stage = [&](int t) {
        int k0 = t * 32 + skg * 8;
        s0 = make_float4(0.f, 0.f, 0.f, 0.f);
        s1 = make_float4(0.f, 0.f, 0.f, 0.f);
        if (sgr < N && k0 + 8 <= DIM_IN) {
            const float* p = &x[(size_t)sgr * DIM_IN + k0];
            s0 = *(const float4*)p;
            s1 = *(const float4*)(p + 4);
        }
    };
    auto store_stage = [&](int buf) {
        uint4 w;
        w.x = pack2(s0.x, s0.y);
        w.y = pack2(s0.z, s0.w);
        w.z = pack2(s1.x, s1.y);
        w.w = pack2(s1.z, s1.w);
        *(uint4*)&a_lds[buf][sidx] = w;
    };

    load_stage(0);
    store_stage(0);
    __syncthreads();

    const s16x8* wp = (const s16x8*)wpack;
    for (int t = 0; t < 32; t++) {
        int cur = t & 1;
        if (t + 1 < 32) load_stage(t + 1);
        s16x8 bf0 = wp[(size_t)(t * 8 + wc * 2 + 0) * 64 + lane];
        s16x8 bf1 = wp[(size_t)(t * 8 + wc * 2 + 1) * 64 + lane];
        s16x8 af0 = *(const s16x8*)&a_lds[cur][(0 * 64 + lane) * 8];
        s16x8 af1 = *(const s16x8*)&a_lds[cur][(1 * 64 + lane) * 8];
        s16x8 af2 = *(const s16x8*)&a_lds[cur][(2 * 64 + lane) * 8];
        s16x8 af3 = *(const s16x8*)&a_lds[cur][(3 * 64 + lane) * 8];
        acc[0][0] = __builtin_amdgcn_mfma_f32_16x16x32_bf16(af0, bf0, acc[0][0], 0, 0, 0);
        acc[0][1] = __builtin_amdgcn_mfma_f32_16x16x32_bf16(af0, bf1, acc[0][1], 0, 0, 0);
        acc[1][0] = __builtin_amdgcn_mfma_f32_16x16x32_bf16(af1, bf0, acc[1][0], 0, 0, 0);
        acc[1][1] = __builtin_amdgcn_mfma_f32_16x16x32_bf16(af1, bf1, acc[1][1], 0, 0, 0);
        acc[2][0] = __builtin_amdgcn_mfma_f32_16x16x32_bf16(af2, bf0, acc[2][0], 0, 0, 0);
        acc[2][1] = __builtin_amdgcn_mfma_f32_16x16x32_bf16(af2, bf1, acc[2][1], 0, 0, 0);
        acc[3][0] = __builtin_amdgcn_mfma_f32_16x16x32_bf16(af3, bf0, acc[3][0], 0, 0, 0);
        acc[3][1] = __builtin_amdgcn_mfma_f32_16x16x32_bf16(af3, bf1, acc[3][1], 0, 0, 0);
        if (t + 1 < 32) store_stage(cur ^ 1);
        __syncthreads();
    }

    const int colbase = wc * 32;
#pragma unroll
    for (int rt = 0; rt < 4; rt++) {
        int gr = rowbase + rt * 16 + ((lane >> 4) * 4);
#pragma unroll
        for (int ctl = 0; ctl < 2; ctl++) {
            int c = colbase + ctl * 16 + (lane & 15);
            float* dst = (c < 64) ? hp1 : p2;
            int cc = (c < 64) ? c : c - 64;
#pragma unroll
            for (int reg = 0; reg < 4; reg++) {
                int r = gr + reg;
                if (r < N) dst[(size_t)r * 64 + cc] = acc[rt][ctl][reg];
            }
        }
    }
}

// ---------------- small GEMM, K=64, NC=64, out += A@W ----------------
__global__ __launch_bounds__(256) void gemm_k64_n64_acc(
    const float* __restrict__ A, const float* __restrict__ W,
    float* __restrict__ out, int N)
{
    __shared__ float as_[16][65];
    const int tid = threadIdx.x;
    const int rb = blockIdx.x * 16;
#pragma unroll
    for (int i = 0; i < 4; i++) {
        int idx = tid + i * 256;
        int r = idx >> 6, c = idx & 63;
        int gr = rb + r;
        as_[r][c] = (gr < N) ? A[(size_t)gr * 64 + c] : 0.f;
    }
    __syncthreads();
    const int row = tid >> 4;
    const int col = (tid & 15) * 4;
    float4 acc = {0, 0, 0, 0};
#pragma unroll 8
    for (int k = 0; k < 64; k++) {
        float a = as_[row][k];
        float4 w = *(const float4*)&W[k * 64 + col];
        acc.x += a * w.x; acc.y += a * w.y; acc.z += a * w.z; acc.w += a * w.w;
    }
    int gr = rb + row;
    if (gr < N) {
        float* o = &out[(size_t)gr * 64 + col];
        o[0] += acc.x; o[1] += acc.y; o[2] += acc.z; o[3] += acc.w;
    }
}

// ---------------- attention dots (per-head h layout [N,H,C], f32) ----------------
template <int C>
__global__ __launch_bounds__(256) void attn_dots(
    const float* __restrict__ h, const float* __restrict__ a_s,
    const float* __restrict__ a_d, float* __restrict__ als,
    float* __restrict__ ald, int NH)
{
    int i = blockIdx.x * blockDim.x + threadIdx.x;
    if (i >= NH) return;
    int head = i & 7;
    const float* hp = h + (size_t)i * C;
    float s = 0.f, d = 0.f;
#pragma unroll
    for (int c = 0; c < C; c++) {
        float v = hp[c];
        s += v * a_s[head * C + c];
        d += v * a_d[head * C + c];
    }
    als[i] = s; ald[i] = d;
}

// ---------------- layer-3 attention dots from bf16 h2 via wtilde ----------------
__global__ __launch_bounds__(512) void make_wtilde(
    const float* __restrict__ W3, const float* __restrict__ as3,
    const float* __restrict__ ad3, float* __restrict__ wts,
    float* __restrict__ wtd)
{
    int t = threadIdx.x;
    int h = t >> 6, k = t & 63;
    float s = 0.f, d = 0.f;
#pragma unroll
    for (int c = 0; c < 32; c++) {
        float w = W3[(size_t)k * 256 + h * 32 + c];
        s += w * as3[h * 32 + c];
        d += w * ad3[h * 32 + c];
    }
    wts[h * 64 + k] = s;
    wtd[h * 64 + k] = d;
}

__global__ __launch_bounds__(256) void attn_dots_w(
    const ushort* __restrict__ h2b, const float* __restrict__ wts,
    const float* __restrict__ wtd, float* __restrict__ als,
    float* __restrict__ ald, int NH)
{
    int i = blockIdx.x * blockDim.x + threadIdx.x;
    if (i >= NH) return;
    int head = i & 7, node = i >> 3;
    const uint4* hp = (const uint4*)(h2b + (size_t)node * 64);
    const float* wsp = wts + head * 64;
    const float* wdp = wtd + head * 64;
    float s = 0.f, d = 0.f;
#pragma unroll
    for (int cq = 0; cq < 8; cq++) {
        uint4 q = hp[cq];
        float f0 = __uint_as_float(q.x << 16), f1 = __uint_as_float(q.x & 0xFFFF0000u);
        float f2 = __uint_as_float(q.y << 16), f3 = __uint_as_float(q.y & 0xFFFF0000u);
        float f4 = __uint_as_float(q.z << 16), f5 = __uint_as_float(q.z & 0xFFFF0000u);
        float f6 = __uint_as_float(q.w << 16), f7 = __uint_as_float(q.w & 0xFFFF0000u);
        int c = cq * 8;
        s += f0 * wsp[c] + f1 * wsp[c + 1] + f2 * wsp[c + 2] + f3 * wsp[c + 3]
           + f4 * wsp[c + 4] + f5 * wsp[c + 5] + f6 * wsp[c + 6] + f7 * wsp[c + 7];
        d += f0 * wdp[c] + f1 * wdp[c + 1] + f2 * wdp[c + 2] + f3 * wdp[c + 3]
           + f4 * wdp[c + 4] + f5 * wdp[c + 5] + f6 * wdp[c + 6] + f7 * wdp[c + 7];
    }
    als[i] = s; ald[i] = d;
}

// ---------------- CSR build ----------------
__global__ __launch_bounds__(256) void csr_hist(
    const int* __restrict__ ei, int E, int Etot, int* __restrict__ deg)
{
    int e = blockIdx.x * blockDim.x + threadIdx.x;
    if (e >= Etot) return;
    int d = (e < E) ? ei[E + e] : e - E;
    atomicAdd(&deg[d], 1);
}

__global__ __launch_bounds__(1024) void csr_scan(
    const int* __restrict__ deg, int* __restrict__ rowptr,
    int* __restrict__ cursor, int N)
{
    __shared__ int partial[1024];
    const int t = threadIdx.x;
    const int chunk = (N + 1023) >> 10;
    const int lo = t * chunk;
    const int hi = min(N, lo + chunk);
    int s = 0;
    for (int i = lo; i < hi; i++) s += deg[i];
    partial[t] = s;
    __syncthreads();
    for (int off = 1; off < 1024; off <<= 1) {
        int v = (t >= off) ? partial[t - off] : 0;
        __syncthreads();
        partial[t] += v;
        __syncthreads();
    }
    int run = (t == 0) ? 0 : partial[t - 1];
    for (int i = lo; i < hi; i++) {
        rowptr[i] = run;
        cursor[i] = run;
        run += deg[i];
    }
    if (t == 1023) rowptr[N] = partial[1023];
}

__global__ __launch_bounds__(256) void csr_fill(
    const int* __restrict__ ei, int E, int Etot,
    int* __restrict__ cursor, int* __restrict__ esrc)
{
    int e = blockIdx.x * blockDim.x + threadIdx.x;
    if (e >= Etot) return;
    int s, d;
    if (e < E) { s = ei[e]; d = ei[E + e]; } else { s = d = e - E; }
    int pos = atomicAdd(&cursor[d], 1);
    esrc[pos] = s;
}

// ---------------- fused gather layer (C=64): 2 nodes per wave, pipelined,
// defer-max online softmax + bias + ELU ----------------
template <bool OUT_BF16>
__global__ __launch_bounds__(256) void gat_gather64(
    const int* __restrict__ rowptr, const int* __restrict__ esrc,
    const float* __restrict__ als, const float* __restrict__ ald,
    const float* __restrict__ h, const float* __restrict__ bias,
    float* __restrict__ outf, ushort* __restrict__ outb, int N)
{
    int wave = (blockIdx.x * 256 + threadIdx.x) >> 6;
    int n0 = wave * 2, n1 = wave * 2 + 1;
    int lane = threadIdx.x & 63;
    int head = lane >> 3;

    int st0 = 0, c0 = 0; float av0 = 0.f;
    if (n0 < N) { st0 = rowptr[n0]; c0 = rowptr[n0 + 1] - st0; av0 = ald[(size_t)n0 * 8 + head]; }
    int st1 = 0, c1 = 0; float av1 = 0.f;
    if (n1 < N) { st1 = rowptr[n1]; c1 = rowptr[n1 + 1] - st1; av1 = ald[(size_t)n1 * 8 + head]; }

    float m0 = -1e30f, d0 = 0.f, a0 = 0.f;
    float m1 = -1e30f, d1 = 0.f, a1 = 0.f;

    auto gi = [&](int st, int c, int k) {
        int kk = (k < c) ? k : c - 1;
        kk = (kk < 0) ? 0 : kk;
        return esrc[st + kk];
    };
    auto idx4 = [&](int st, int c, int k) {
        int4 r; r.x = gi(st, c, k); r.y = gi(st, c, k + 1);
        r.z = gi(st, c, k + 2); r.w = gi(st, c, k + 3);
        return r;
    };
    auto issue = [&](int4 s, float4& ee, float4& hh) {
        ee.x = als[(size_t)s.x * 8 + head];
        ee.y = als[(size_t)s.y * 8 + head];
        ee.z = als[(size_t)s.z * 8 + head];
        ee.w = als[(size_t)s.w * 8 + head];
        hh.x = h[(size_t)s.x * 64 + lane];
        hh.y = h[(size_t)s.y * 64 + lane];
        hh.z = h[(size_t)s.z * 64 + lane];
        hh.w = h[(size_t)s.w * 64 + lane];
    };
    auto upedge = [&](float e, float hv, float& m, float& d, float& a) {
        if (__any(e - m > RESCALE_THR)) {
            float nm = fmaxf(m, e), sc = __expf(m - nm);
            a *= sc; d *= sc; m = nm;
        }
        float ee = __expf(e - m);
        d += ee; a = fmaf(ee, hv, a);
    };
    auto upd = [&](int base, int c, float av, float4 ee, float4 hh,
                   float& m, float& d, float& a) {
        if (base >= c) return;
        float e;
        e = ee.x + av; e = (e > 0.f) ? e : NEG_SLOPE * e; e = (base + 0 < c) ? e : -1e30f;
        upedge(e, hh.x, m, d, a);
        e = ee.y + av; e = (e > 0.f) ? e : NEG_SLOPE * e; e = (base + 1 < c) ? e : -1e30f;
        upedge(e, hh.y, m, d, a);
        e = ee.z + av; e = (e > 0.f) ? e : NEG_SLOPE * e; e = (base + 2 < c) ? e : -1e30f;
        upedge(e, hh.z, m, d, a);
        e = ee.w + av; e = (e > 0.f) ? e : NEG_SLOPE * e; e = (base + 3 < c) ? e : -1e30f;
        upedge(e, hh.w, m, d, a);
    };

    int4 iA0 = idx4(st0, c0, 0), iA1 = idx4(st1, c1, 0);
    float4 eA0, hA0, eA1, hA1, eB0, hB0, eB1, hB1;
    issue(iA0, eA0, hA0); issue(iA1, eA1, hA1);
    int4 iB0 = idx4(st0, c0, 4), iB1 = idx4(st1, c1, 4);
    int cmax = max(c0, c1);
    int nb = (cmax + 3) >> 2;
    for (int b = 0; b < nb; b += 2) {
        issue(iB0, eB0, hB0); issue(iB1, eB1, hB1);
        iA0 = idx4(st0, c0, (b + 2) * 4); iA1 = idx4(st1, c1, (b + 2) * 4);
        upd(b * 4, c0, av0, eA0, hA0, m0, d0, a0);
        upd(b * 4, c1, av1, eA1, hA1, m1, d1, a1);
        issue(iA0, eA0, hA0); issue(iA1, eA1, hA1);
        iB0 = idx4(st0, c0, (b + 3) * 4); iB1 = idx4(st1, c1, (b + 3) * 4);
        upd((b + 1) * 4, c0, av0, eB0, hB0, m0, d0, a0);
        upd((b + 1) * 4, c1, av1, eB1, hB1, m1, d1, a1);
    }
    if (n0 < N) {
        float v = a0 / (d0 + 1e-16f) + bias[lane];
        v = (v > 0.f) ? v : (__expf(v) - 1.f);
        if (OUT_BF16) outb[(size_t)n0 * 64 + lane] = (ushort)bf16rne(v);
        else outf[(size_t)n0 * 64 + lane] = v;
    }
    if (n1 < N) {
        float v = a1 / (d1 + 1e-16f) + bias[lane];
        v = (v > 0.f) ? v : (__expf(v) - 1.f);
        if (OUT_BF16) outb[(size_t)n1 * 64 + lane] = (ushort)bf16rne(v);
        else outf[(size_t)n1 * 64 + lane] = v;
    }
}

// ---------------- layer 3 fully fused: 2 nodes per wave, pipelined bf16-h2
// gather + defer-max, tiny per-head GEMM with W3, head-mean, bias, log_softmax ----
__global__ __launch_bounds__(256) void gat_l3_final(
    const int* __restrict__ rowptr, const int* __restrict__ esrc,
    const float* __restrict__ als, const float* __restrict__ ald,
    const ushort* __restrict__ h2b, const float* __restrict__ W3,
    const float* __restrict__ b3, float* __restrict__ out, int N)
{
    int wave = (blockIdx.x * 256 + threadIdx.x) >> 6;
    int n0 = wave * 2, n1 = wave * 2 + 1;
    int lane = threadIdx.x & 63;
    int h = lane >> 3, c8 = lane & 7;

    int st0 = 0, c0 = 0; float av0 = 0.f;
    if (n0 < N) { st0 = rowptr[n0]; c0 = rowptr[n0 + 1] - st0; av0 = ald[(size_t)n0 * 8 + h]; }
    int st1 = 0, c1 = 0; float av1 = 0.f;
    if (n1 < N) { st1 = rowptr[n1]; c1 = rowptr[n1 + 1] - st1; av1 = ald[(size_t)n1 * 8 + h]; }

    float m0 = -1e30f, d0 = 0.f, m1 = -1e30f, d1 = 0.f;
    float acc0[8] = {}, acc1[8] = {};

    auto gi = [&](int st, int c, int k) {
        int kk = (k < c) ? k : c - 1;
        kk = (kk < 0) ? 0 : kk;
        return esrc[st + kk];
    };
    auto idx4 = [&](int st, int c, int k) {
        int4 r; r.x = gi(st, c, k); r.y = gi(st, c, k + 1);
        r.z = gi(st, c, k + 2); r.w = gi(st, c, k + 3);
        return r;
    };
    auto issue = [&](int4 s, float4& ee, uint4& q0, uint4& q1, uint4& q2, uint4& q3) {
        ee.x = als[(size_t)s.x * 8 + h];
        ee.y = als[(size_t)s.y * 8 + h];
        ee.z = als[(size_t)s.z * 8 + h];
        ee.w = als[(size_t)s.w * 8 + h];
        q0 = *(const uint4*)&h2b[(size_t)s.x * 64 + c8 * 8];
        q1 = *(const uint4*)&h2b[(size_t)s.y * 64 + c8 * 8];
        q2 = *(const uint4*)&h2b[(size_t)s.z * 64 + c8 * 8];
        q3 = *(const uint4*)&h2b[(size_t)s.w * 64 + c8 * 8];
    };
    auto upedge = [&](float e, uint4 q, float& m, float& d, float (&a)[8]) {
        if (__any(e - m > RESCALE_THR)) {
            float nm = fmaxf(m, e), sc = __expf(m - nm);
            d *= sc;
#pragma unroll
            for (int j = 0; j < 8; j++) a[j] *= sc;
            m = nm;
        }
        float ee = __expf(e - m);
        d += ee;
        a[0] = fmaf(ee, __uint_as_float(q.x << 16), a[0]);
        a[1] = fmaf(ee, __uint_as_float(q.x & 0xFFFF0000u), a[1]);
        a[2] = fmaf(ee, __uint_as_float(q.y << 16), a[2]);
        a[3] = fmaf(ee, __uint_as_float(q.y & 0xFFFF0000u), a[3]);
        a[4] = fmaf(ee, __uint_as_float(q.z << 16), a[4]);
        a[5] = fmaf(ee, __uint_as_float(q.z & 0xFFFF0000u), a[5]);
        a[6] = fmaf(ee, __uint_as_float(q.w << 16), a[6]);
        a[7] = fmaf(ee, __uint_as_float(q.w & 0xFFFF0000u), a[7]);
    };
    auto upd = [&](int base, int c, float av, float4 ee,
                   uint4 q0, uint4 q1, uint4 q2, uint4 q3,
                   float& m, float& d, float (&a)[8]) {
        if (base >= c) return;
        float e;
        e = ee.x + av; e = (e > 0.f) ? e : NEG_SLOPE * e; e = (base + 0 < c) ? e : -1e30f;
        upedge(e, q0, m, d, a);
        e = ee.y + av; e = (e > 0.f) ? e : NEG_SLOPE * e; e = (base + 1 < c) ? e : -1e30f;
        upedge(e, q1, m, d, a);
        e = ee.z + av; e = (e > 0.f) ? e : NEG_SLOPE * e; e = (base + 2 < c) ? e : -1e30f;
        upedge(e, q2, m, d, a);
        e = ee.w + av; e = (e > 0.f) ? e : NEG_SLOPE * e; e = (base + 3 < c) ? e : -1e30f;
        upedge(e, q3, m, d, a);
    };

    int4 iA0 = idx4(st0, c0, 0), iA1 = idx4(st1, c1, 0);
    float4 eA0, eA1, eB0, eB1;
    uint4 qA00, qA01, qA02, qA03, qA10, qA11, qA12, qA13;
    uint4 qB00, qB01, qB02, qB03, qB10, qB11, qB12, qB13;
    issue(iA0, eA0, qA00, qA01, qA02, qA03);
    issue(iA1, eA1, qA10, qA11, qA12, qA13);
    int4 iB0 = idx4(st0, c0, 4), iB1 = idx4(st1, c1, 4);
    int cmax = max(c0, c1);
    int nb = (cmax + 3) >> 2;
    for (int b = 0; b < nb; b += 2) {
        issue(iB0, eB0, qB00, qB01, qB02, qB03);
        issue(iB1, eB1, qB10, qB11, qB12, qB13);
        iA0 = idx4(st0, c0, (b + 2) * 4); iA1 = idx4(st1, c1, (b + 2) * 4);
        upd(b * 4, c0, av0, eA0, qA00, qA01, qA02, qA03, m0, d0, acc0);
        upd(b * 4, c1, av1, eA1, qA10, qA11, qA12, qA13, m1, d1, acc1);
        issue(iA0, eA0, qA00, qA01, qA02, qA03);
        issue(iA1, eA1, qA10, qA11, qA12, qA13);
        iB0 = idx4(st0, c0, (b + 3) * 4); iB1 = idx4(st1, c1, (b + 3) * 4);
        upd((b + 1) * 4, c0, av0, eB0, qB00, qB01, qB02, qB03, m0, d0, acc0);
        upd((b + 1) * 4, c1, av1, eB1, qB10, qB11, qB12, qB13, m1, d1, acc1);
    }

    auto finalize = [&](int node, float dd, float (&ac)[8]) {
        float inv = 1.f / (dd + 1e-16f);
        float acn[8];
#pragma unroll
        for (int j = 0; j < 8; j++) acn[j] = ac[j] * inv;
        float4 o4 = {0.f, 0.f, 0.f, 0.f};
#pragma unroll
        for (int r = 0; r < 8; r++) {
#pragma unroll
            for (int j = 0; j < 8; j++) {
                float a = __shfl(acn[j], h * 8 + r, 64);
                int k = r * 8 + j;
                float4 w = *(const float4*)&W3[(size_t)k * 256 + h * 32 + c8 * 4];
                o4.x += a * w.x; o4.y += a * w.y; o4.z += a * w.z; o4.w += a * w.w;
            }
        }
#pragma unroll
        for (int o = 8; o < 64; o <<= 1) {
            o4.x += __shfl_xor(o4.x, o, 64);
            o4.y += __shfl_xor(o4.y, o, 64);
            o4.z += __shfl_xor(o4.z, o, 64);
            o4.w += __shfl_xor(o4.w, o, 64);
        }
        int cq = c8 * 4;
        o4.x = o4.x * 0.125f + b3[cq + 0];
        o4.y = o4.y * 0.125f + b3[cq + 1];
        o4.z = o4.z * 0.125f + b3[cq + 2];
        o4.w = o4.w * 0.125f + b3[cq + 3];
        float mx = fmaxf(fmaxf(o4.x, o4.y), fmaxf(o4.z, o4.w));
#pragma unroll
        for (int o = 1; o < 8; o <<= 1) mx = fmaxf(mx, __shfl_xor(mx, o, 64));
        float ex = __expf(o4.x - mx) + __expf(o4.y - mx) + __expf(o4.z - mx) + __expf(o4.w - mx);
#pragma unroll
        for (int o = 1; o < 8; o <<= 1) ex += __shfl_xor(ex, o, 64);
        float lse = mx + __logf(ex);
        if (lane < 8) {
            float4 r4 = {o4.x - lse, o4.y - lse, o4.z - lse, o4.w - lse};
            *(float4*)&out[(size_t)node * 32 + cq] = r4;
        }
    };
    if (n0 < N) finalize(n0, d0, acc0);
    if (n1 < N) finalize(n1, d1, acc1);
}

// ---------------- host launch ----------------
extern "C" void kernel_launch(void* const* d_in, const int* in_sizes, int n_in,
                              void* d_out, int out_size, void* d_ws, size_t ws_size,
                              hipStream_t stream)
{
    const float* x   = (const float*)d_in[0];
    const int*   ei  = (const int*)  d_in[1];
    const float* W1  = (const float*)d_in[2];
    const float* as1 = (const float*)d_in[3];
    const float* ad1 = (const float*)d_in[4];
    const float* b1  = (const float*)d_in[5];
    const float* W2  = (const float*)d_in[6];
    const float* as2 = (const float*)d_in[7];
    const float* ad2 = (const float*)d_in[8];
    const float* b2  = (const float*)d_in[9];
    const float* W3  = (const float*)d_in[10];
    const float* as3 = (const float*)d_in[11];
    const float* ad3 = (const float*)d_in[12];
    const float* b3  = (const float*)d_in[13];
    float* out = (float*)d_out;

    const int N = in_sizes[0] / DIM_IN;
    const int E = in_sizes[1] / 2;
    const int Etot = E + N;

    float* ws = (float*)d_ws;
    size_t o = 0;
    float* hp1 = ws + o; o += (size_t)N * 64;
    float* p2  = ws + o; o += (size_t)N * 64;
    float* h1  = ws + o; o += (size_t)N * 64;
    ushort* h2b = (ushort*)(ws + o); o += (size_t)N * 32;   // bf16 h2
    float* als = ws + o; o += (size_t)N * 8;
    float* ald = ws + o; o += (size_t)N * 8;
    float* wts = ws + o; o += 512;
    float* wtd = ws + o; o += 512;
    ushort* wpack = (ushort*)(ws + o); o += 32768;
    int* deg    = (int*)(ws + o); o += N;
    int* rowptr = (int*)(ws + o); o += N + 1;
    int* cursor = (int*)(ws + o); o += N;
    int* esrc   = (int*)(ws + o); o += Etot;
    if (o * 4 > ws_size) return;

    const int TB = 256;
    const int NPB = 8;   // nodes per block (4 waves x 2)

    pack_w<<<64, TB, 0, stream>>>(W1, W2, wpack);
    gemm1_mfma<<<(N + 63) / 64, TB, 0, stream>>>(x, wpack, hp1, p2, N);

    hipMemsetAsync(deg, 0, (size_t)N * 4, stream);
    csr_hist<<<(Etot + TB - 1) / TB, TB, 0, stream>>>(ei, E, Etot, deg);
    csr_scan<<<1, 1024, 0, stream>>>(deg, rowptr, cursor, N);
    csr_fill<<<(Etot + TB - 1) / TB, TB, 0, stream>>>(ei, E, Etot, cursor, esrc);

    // ---- layer 1 ----
    attn_dots<8><<<(N * 8 + TB - 1) / TB, TB, 0, stream>>>(hp1, as1, ad1, als, ald, N * 8);
    gat_gather64<false><<<(N + NPB - 1) / NPB, TB, 0, stream>>>(rowptr, esrc, als, ald, hp1, b1, h1, nullptr, N);

    // p2 += h1 @ W2[1000:1064]
    gemm_k64_n64_acc<<<(N + 15) / 16, TB, 0, stream>>>(h1, W2 + (size_t)DIM_IN * 64, p2, N);

    // ---- layer 2 (bf16 output) ----
    attn_dots<8><<<(N * 8 + TB - 1) / TB, TB, 0, stream>>>(p2, as2, ad2, als, ald, N * 8);
    gat_gather64<true><<<(N + NPB - 1) / NPB, TB, 0, stream>>>(rowptr, esrc, als, ald, p2, b2, nullptr, h2b, N);

    // ---- layer 3 ----
    make_wtilde<<<1, 512, 0, stream>>>(W3, as3, ad3, wts, wtd);
    attn_dots_w<<<(N * 8 + TB - 1) / TB, TB, 0, stream>>>(h2b, wts, wtd, als, ald, N * 8);
    gat_l3_final<<<(N + NPB - 1) / NPB, TB, 0, stream>>>(rowptr, esrc, als, ald, h2b, W3, b3, out, N);
}

// Round 9
// 522.334 us; speedup vs baseline: 1.1607x; 1.1607x over previous
//
#include <hip/hip_runtime.h>
#include <hip/hip_bf16.h>

// ---------------- constants (match reference) ----------------
#define DIM_IN 1000
#define HEADS 8
#define HID 8
#define DIM_OUT 32
#define NEG_SLOPE 0.2f
#define RESCALE_THR 8.f

typedef __attribute__((ext_vector_type(4))) float f32x4;
typedef __attribute__((ext_vector_type(8))) short s16x8;

__device__ __forceinline__ unsigned bf16rne(float f) {
    unsigned u = __float_as_uint(f);
    return (u + 0x7FFFu + ((u >> 16) & 1u)) >> 16;
}
__device__ __forceinline__ unsigned pack2(float lo, float hi) {
    return bf16rne(lo) | (bf16rne(hi) << 16);
}
__device__ __forceinline__ float bflo(unsigned u) { return __uint_as_float(u << 16); }
__device__ __forceinline__ float bfhi(unsigned u) { return __uint_as_float(u & 0xFFFF0000u); }
__device__ __forceinline__ float bf1(ushort u) { return __uint_as_float((unsigned)u << 16); }

// ---------------- W pre-pack: fragment-ordered bf16 [32 kt][8 ctg][64 lane][8] ----
__global__ __launch_bounds__(256) void pack_w(
    const float* __restrict__ W1, const float* __restrict__ W2,
    ushort* __restrict__ wpack)
{
    int t = blockIdx.x * 256 + threadIdx.x;   // 0..16383
    if (t >= 32 * 8 * 64) return;
    int lane = t & 63;
    int ctg = (t >> 6) & 7;
    int kt = t >> 9;
    int c = ctg * 16 + (lane & 15);
    int kbase = kt * 32 + (lane >> 4) * 8;
    ushort v[8] __attribute__((aligned(16)));
#pragma unroll
    for (int j = 0; j < 8; j++) {
        int k = kbase + j;
        float w = 0.f;
        if (k < DIM_IN) w = (c < 64) ? W1[(size_t)k * 64 + c] : W2[(size_t)k * 64 + (c - 64)];
        v[j] = (ushort)bf16rne(w);
    }
    *(uint4*)&wpack[(size_t)t * 8] = *(const uint4*)v;
}

// ---------------- W3 pre-pack: [2 kt][16 ctg][64 lane][8] ----
__global__ __launch_bounds__(256) void pack_w3(
    const float* __restrict__ W3, ushort* __restrict__ w3pack)
{
    int t = blockIdx.x * 256 + threadIdx.x;   // 0..2047
    if (t >= 2 * 16 * 64) return;
    int lane = t & 63;
    int ctg = (t >> 6) & 15;
    int kt = t >> 10;
    int c = ctg * 16 + (lane & 15);
    int kbase = kt * 32 + (lane >> 4) * 8;
    ushort v[8] __attribute__((aligned(16)));
#pragma unroll
    for (int j = 0; j < 8; j++)
        v[j] = (ushort)bf16rne(W3[(size_t)(kbase + j) * 256 + c]);
    *(uint4*)&w3pack[(size_t)t * 8] = *(const uint4*)v;
}

// ---------------- GEMM1 (MFMA bf16): x[N,1000] @ [W1|W2a] -> hp1b(bf16), p2(f32) ----
__global__ __launch_bounds__(256) void gemm1_mfma(
    const float* __restrict__ x, const ushort* __restrict__ wpack,
    ushort* __restrict__ hp1b, float* __restrict__ p2, int N)
{
    __shared__ __align__(16) ushort a_lds[2][64 * 32];
    const int tid = threadIdx.x;
    const int lane = tid & 63;
    const int wc = tid >> 6;
    const int rowbase = blockIdx.x * 64;

    const int srow = tid >> 2;
    const int skg = tid & 3;
    const int sgr = rowbase + srow;
    const int sidx = ((srow >> 4) * 64 + skg * 16 + (srow & 15)) * 8;

    f32x4 acc[4][2];
#pragma unroll
    for (int i = 0; i < 4; i++)
#pragma unroll
        for (int j = 0; j < 2; j++) acc[i][j] = (f32x4){0.f, 0.f, 0.f, 0.f};

    float4 s0, s1;
    auto load_stage = [&](int t) {
        int k0 = t * 32 + skg * 8;
        s0 = make_float4(0.f, 0.f, 0.f, 0.f);
        s1 = make_float4(0.f, 0.f, 0.f, 0.f);
        if (sgr < N && k0 + 8 <= DIM_IN) {
            const float* p = &x[(size_t)sgr * DIM_IN + k0];
            s0 = *(const float4*)p;
            s1 = *(const float4*)(p + 4);
        }
    };
    auto store_stage = [&](int buf) {
        uint4 w;
        w.x = pack2(s0.x, s0.y);
        w.y = pack2(s0.z, s0.w);
        w.z = pack2(s1.x, s1.y);
        w.w = pack2(s1.z, s1.w);
        *(uint4*)&a_lds[buf][sidx] = w;
    };

    load_stage(0);
    store_stage(0);
    __syncthreads();

    const s16x8* wp = (const s16x8*)wpack;
    for (int t = 0; t < 32; t++) {
        int cur = t & 1;
        if (t + 1 < 32) load_stage(t + 1);
        s16x8 bf0 = wp[(size_t)(t * 8 + wc * 2 + 0) * 64 + lane];
        s16x8 bf1 = wp[(size_t)(t * 8 + wc * 2 + 1) * 64 + lane];
        s16x8 af0 = *(const s16x8*)&a_lds[cur][(0 * 64 + lane) * 8];
        s16x8 af1 = *(const s16x8*)&a_lds[cur][(1 * 64 + lane) * 8];
        s16x8 af2 = *(const s16x8*)&a_lds[cur][(2 * 64 + lane) * 8];
        s16x8 af3 = *(const s16x8*)&a_lds[cur][(3 * 64 + lane) * 8];
        acc[0][0] = __builtin_amdgcn_mfma_f32_16x16x32_bf16(af0, bf0, acc[0][0], 0, 0, 0);
        acc[0][1] = __builtin_amdgcn_mfma_f32_16x16x32_bf16(af0, bf1, acc[0][1], 0, 0, 0);
        acc[1][0] = __builtin_amdgcn_mfma_f32_16x16x32_bf16(af1, bf0, acc[1][0], 0, 0, 0);
        acc[1][1] = __builtin_amdgcn_mfma_f32_16x16x32_bf16(af1, bf1, acc[1][1], 0, 0, 0);
        acc[2][0] = __builtin_amdgcn_mfma_f32_16x16x32_bf16(af2, bf0, acc[2][0], 0, 0, 0);
        acc[2][1] = __builtin_amdgcn_mfma_f32_16x16x32_bf16(af2, bf1, acc[2][1], 0, 0, 0);
        acc[3][0] = __builtin_amdgcn_mfma_f32_16x16x32_bf16(af3, bf0, acc[3][0], 0, 0, 0);
        acc[3][1] = __builtin_amdgcn_mfma_f32_16x16x32_bf16(af3, bf1, acc[3][1], 0, 0, 0);
        if (t + 1 < 32) store_stage(cur ^ 1);
        __syncthreads();
    }

    const int colbase = wc * 32;
#pragma unroll
    for (int rt = 0; rt < 4; rt++) {
        int gr = rowbase + rt * 16 + ((lane >> 4) * 4);
#pragma unroll
        for (int ctl = 0; ctl < 2; ctl++) {
            int c = colbase + ctl * 16 + (lane & 15);
#pragma unroll
            for (int reg = 0; reg < 4; reg++) {
                int r = gr + reg;
                if (r >= N) continue;
                float v = acc[rt][ctl][reg];
                if (c < 64) hp1b[(size_t)r * 64 + c] = (ushort)bf16rne(v);
                else        p2[(size_t)r * 64 + (c - 64)] = v;
            }
        }
    }
}

// ---------------- GEMM3 (MFMA bf16): h3pb[N,256] = h2b[N,64] @ W3 ----------------
// block = 4 waves, 16 rows; wave wc covers cols wc*64..wc*64+63.
__global__ __launch_bounds__(256) void gemm3_mfma(
    const ushort* __restrict__ h2b, const ushort* __restrict__ w3pack,
    ushort* __restrict__ h3pb, int N)
{
    const int tid = threadIdx.x;
    const int lane = tid & 63;
    const int wc = tid >> 6;
    const int rowbase = blockIdx.x * 16;
    const int arow = rowbase + (lane & 15);

    f32x4 acc[4];
#pragma unroll
    for (int i = 0; i < 4; i++) acc[i] = (f32x4){0.f, 0.f, 0.f, 0.f};

    const s16x8* wp = (const s16x8*)w3pack;
#pragma unroll
    for (int kt = 0; kt < 2; kt++) {
        s16x8 af = (s16x8){0, 0, 0, 0, 0, 0, 0, 0};
        if (arow < N)
            af = *(const s16x8*)&h2b[(size_t)arow * 64 + kt * 32 + (lane >> 4) * 8];
#pragma unroll
        for (int ct = 0; ct < 4; ct++) {
            s16x8 bf = wp[(size_t)(kt * 16 + wc * 4 + ct) * 64 + lane];
            acc[ct] = __builtin_amdgcn_mfma_f32_16x16x32_bf16(af, bf, acc[ct], 0, 0, 0);
        }
    }
#pragma unroll
    for (int ct = 0; ct < 4; ct++) {
        int col = wc * 64 + ct * 16 + (lane & 15);
        int gr = rowbase + (lane >> 4) * 4;
#pragma unroll
        for (int reg = 0; reg < 4; reg++) {
            int r = gr + reg;
            if (r < N) h3pb[(size_t)r * 256 + col] = (ushort)bf16rne(acc[ct][reg]);
        }
    }
}

// ---------------- small GEMM, K=64, NC=64: h2pre_b = bf16(p2 + h1@W2b) ----------------
__global__ __launch_bounds__(256) void gemm_k64_n64_acc(
    const float* __restrict__ A, const float* __restrict__ W,
    const float* __restrict__ P, ushort* __restrict__ outb, int N)
{
    __shared__ float as_[16][65];
    const int tid = threadIdx.x;
    const int rb = blockIdx.x * 16;
#pragma unroll
    for (int i = 0; i < 4; i++) {
        int idx = tid + i * 256;
        int r = idx >> 6, c = idx & 63;
        int gr = rb + r;
        as_[r][c] = (gr < N) ? A[(size_t)gr * 64 + c] : 0.f;
    }
    __syncthreads();
    const int row = tid >> 4;
    const int col = (tid & 15) * 4;
    float4 acc = {0, 0, 0, 0};
#pragma unroll 8
    for (int k = 0; k < 64; k++) {
        float a = as_[row][k];
        float4 w = *(const float4*)&W[k * 64 + col];
        acc.x += a * w.x; acc.y += a * w.y; acc.z += a * w.z; acc.w += a * w.w;
    }
    int gr = rb + row;
    if (gr < N) {
        float4 p = *(const float4*)&P[(size_t)gr * 64 + col];
        float v0 = p.x + acc.x, v1 = p.y + acc.y, v2 = p.z + acc.z, v3 = p.w + acc.w;
        *(uint*)&outb[(size_t)gr * 64 + col] = pack2(v0, v1);
        *(uint*)&outb[(size_t)gr * 64 + col + 2] = pack2(v2, v3);
    }
}

// ---------------- attention dots, bf16 rows, per-head C=8 ----------------
__global__ __launch_bounds__(256) void attn_dots_b8(
    const ushort* __restrict__ hb, const float* __restrict__ a_s,
    const float* __restrict__ a_d, float* __restrict__ als,
    float* __restrict__ ald, int NH)
{
    int i = blockIdx.x * blockDim.x + threadIdx.x;   // node*8 + head
    if (i >= NH) return;
    int head = i & 7;
    uint4 q = *(const uint4*)&hb[(size_t)i * 8];
    float f[8] = {bflo(q.x), bfhi(q.x), bflo(q.y), bfhi(q.y),
                  bflo(q.z), bfhi(q.z), bflo(q.w), bfhi(q.w)};
    const float* ap = a_s + head * 8;
    const float* dp = a_d + head * 8;
    float s = 0.f, d = 0.f;
#pragma unroll
    for (int c = 0; c < 8; c++) { s += f[c] * ap[c]; d += f[c] * dp[c]; }
    als[i] = s; ald[i] = d;
}

// ---------------- layer-3 attention dots from bf16 h2 via wtilde ----------------
__global__ __launch_bounds__(512) void make_wtilde(
    const float* __restrict__ W3, const float* __restrict__ as3,
    const float* __restrict__ ad3, float* __restrict__ wts,
    float* __restrict__ wtd)
{
    int t = threadIdx.x;
    int h = t >> 6, k = t & 63;
    float s = 0.f, d = 0.f;
#pragma unroll
    for (int c = 0; c < 32; c++) {
        float w = W3[(size_t)k * 256 + h * 32 + c];
        s += w * as3[h * 32 + c];
        d += w * ad3[h * 32 + c];
    }
    wts[h * 64 + k] = s;
    wtd[h * 64 + k] = d;
}

__global__ __launch_bounds__(256) void attn_dots_w(
    const ushort* __restrict__ h2b, const float* __restrict__ wts,
    const float* __restrict__ wtd, float* __restrict__ als,
    float* __restrict__ ald, int NH)
{
    int i = blockIdx.x * blockDim.x + threadIdx.x;
    if (i >= NH) return;
    int head = i & 7, node = i >> 3;
    const uint4* hp = (const uint4*)(h2b + (size_t)node * 64);
    const float* wsp = wts + head * 64;
    const float* wdp = wtd + head * 64;
    float s = 0.f, d = 0.f;
#pragma unroll
    for (int cq = 0; cq < 8; cq++) {
        uint4 q = hp[cq];
        float f0 = bflo(q.x), f1 = bfhi(q.x), f2 = bflo(q.y), f3 = bfhi(q.y);
        float f4 = bflo(q.z), f5 = bfhi(q.z), f6 = bflo(q.w), f7 = bfhi(q.w);
        int c = cq * 8;
        s += f0 * wsp[c] + f1 * wsp[c + 1] + f2 * wsp[c + 2] + f3 * wsp[c + 3]
           + f4 * wsp[c + 4] + f5 * wsp[c + 5] + f6 * wsp[c + 6] + f7 * wsp[c + 7];
        d += f0 * wdp[c] + f1 * wdp[c + 1] + f2 * wdp[c + 2] + f3 * wdp[c + 3]
           + f4 * wdp[c + 4] + f5 * wdp[c + 5] + f6 * wdp[c + 6] + f7 * wdp[c + 7];
    }
    als[i] = s; ald[i] = d;
}

// ---------------- CSR build ----------------
__global__ __launch_bounds__(256) void csr_hist(
    const int* __restrict__ ei, int E, int Etot, int* __restrict__ deg)
{
    int e = blockIdx.x * blockDim.x + threadIdx.x;
    if (e >= Etot) return;
    int d = (e < E) ? ei[E + e] : e - E;
    atomicAdd(&deg[d], 1);
}

__global__ __launch_bounds__(1024) void csr_scan(
    const int* __restrict__ deg, int* __restrict__ rowptr,
    int* __restrict__ cursor, int N)
{
    __shared__ int partial[1024];
    const int t = threadIdx.x;
    const int chunk = (N + 1023) >> 10;
    const int lo = t * chunk;
    const int hi = min(N, lo + chunk);
    int s = 0;
    for (int i = lo; i < hi; i++) s += deg[i];
    partial[t] = s;
    __syncthreads();
    for (int off = 1; off < 1024; off <<= 1) {
        int v = (t >= off) ? partial[t - off] : 0;
        __syncthreads();
        partial[t] += v;
        __syncthreads();
    }
    int run = (t == 0) ? 0 : partial[t - 1];
    for (int i = lo; i < hi; i++) {
        rowptr[i] = run;
        cursor[i] = run;
        run += deg[i];
    }
    if (t == 1023) rowptr[N] = partial[1023];
}

__global__ __launch_bounds__(256) void csr_fill(
    const int* __restrict__ ei, int E, int Etot,
    int* __restrict__ cursor, int* __restrict__ esrc)
{
    int e = blockIdx.x * blockDim.x + threadIdx.x;
    if (e >= Etot) return;
    int s, d;
    if (e < E) { s = ei[e]; d = ei[E + e]; } else { s = d = e - E; }
    int pos = atomicAdd(&cursor[d], 1);
    esrc[pos] = s;
}

// ---------------- fused gather layer (C=64, bf16 rows): pipelined, 2-stream
// defer-max online softmax + bias + ELU ----------------
template <bool OUT_BF16>
__global__ __launch_bounds__(256) void gat_gather64(
    const int* __restrict__ rowptr, const int* __restrict__ esrc,
    const float* __restrict__ als, const float* __restrict__ ald,
    const ushort* __restrict__ hb, const float* __restrict__ bias,
    float* __restrict__ outf, ushort* __restrict__ outb, int N)
{
    int node = blockIdx.x * 4 + (threadIdx.x >> 6);
    if (node >= N) return;
    int lane = threadIdx.x & 63;
    int head = lane >> 3;
    int start = rowptr[node];
    int cnt = rowptr[node + 1] - start;
    float aldv = ald[(size_t)node * 8 + head];

    float mA = -1e30f, dA = 0.f, aA = 0.f;
    float mB = -1e30f, dB = 0.f, aB = 0.f;

    auto gi = [&](int k) { return esrc[start + (k < cnt ? k : cnt - 1)]; };
    auto idx4 = [&](int k) {
        int4 r; r.x = gi(k); r.y = gi(k + 1); r.z = gi(k + 2); r.w = gi(k + 3);
        return r;
    };
    auto issue = [&](int4 s, float4& ee, float4& hh) {
        ee.x = als[(size_t)s.x * 8 + head];
        ee.y = als[(size_t)s.y * 8 + head];
        ee.z = als[(size_t)s.z * 8 + head];
        ee.w = als[(size_t)s.w * 8 + head];
        hh.x = bf1(hb[(size_t)s.x * 64 + lane]);
        hh.y = bf1(hb[(size_t)s.y * 64 + lane]);
        hh.z = bf1(hb[(size_t)s.z * 64 + lane]);
        hh.w = bf1(hb[(size_t)s.w * 64 + lane]);
    };
    auto upedge = [&](float e, float hv, float& m, float& d, float& a) {
        if (__any(e - m > RESCALE_THR)) {
            float nm = fmaxf(m, e), sc = __expf(m - nm);
            a *= sc; d *= sc; m = nm;
        }
        float ee = __expf(e - m);
        d += ee; a = fmaf(ee, hv, a);
    };
    auto lrelu = [&](float e, int k) {
        e += aldv;
        e = (e > 0.f) ? e : NEG_SLOPE * e;
        return (k < cnt) ? e : -1e30f;
    };
    auto upd = [&](int base, float4 ee, float4 hh) {
        if (base >= cnt) return;
        upedge(lrelu(ee.x, base + 0), hh.x, mA, dA, aA);
        upedge(lrelu(ee.y, base + 1), hh.y, mA, dA, aA);
        upedge(lrelu(ee.z, base + 2), hh.z, mB, dB, aB);
        upedge(lrelu(ee.w, base + 3), hh.w, mB, dB, aB);
    };

    int4 i0 = idx4(0), i1 = idx4(4);
    float4 e0, h0, e1, h1;
    issue(i0, e0, h0);
    int nb = (cnt + 3) >> 2;
    for (int b = 0; b < nb; b += 2) {
        i0 = idx4((b + 2) * 4);
        issue(i1, e1, h1);
        upd(b * 4, e0, h0);
        i1 = idx4((b + 3) * 4);
        issue(i0, e0, h0);
        upd((b + 1) * 4, e1, h1);
    }
    float m = fmaxf(mA, mB);
    float sA = __expf(mA - m), sB = __expf(mB - m);
    float den = dA * sA + dB * sB;
    float acc = aA * sA + aB * sB;
    float v = acc / (den + 1e-16f) + bias[lane];
    v = (v > 0.f) ? v : (__expf(v) - 1.f);
    if (OUT_BF16) outb[(size_t)node * 64 + lane] = (ushort)bf16rne(v);
    else outf[(size_t)node * 64 + lane] = v;
}

// ---------------- layer 3: gather bf16 h3p rows (8B/lane/edge), defer-max,
// head-mean + bias + log_softmax. One wave per node. ----------------
__global__ __launch_bounds__(256) void gat_l3_final(
    const int* __restrict__ rowptr, const int* __restrict__ esrc,
    const float* __restrict__ als, const float* __restrict__ ald,
    const ushort* __restrict__ h3pb, const float* __restrict__ b3,
    float* __restrict__ out, int N)
{
    int node = blockIdx.x * 4 + (threadIdx.x >> 6);
    if (node >= N) return;
    int lane = threadIdx.x & 63;
    int h = lane >> 3, c8 = lane & 7;
    int loff = h * 32 + c8 * 4;
    int start = rowptr[node];
    int cnt = rowptr[node + 1] - start;
    float aldv = ald[(size_t)node * 8 + h];

    float mA = -1e30f, dA = 0.f, mB = -1e30f, dB = 0.f;
    float4 accA = {0, 0, 0, 0}, accB = {0, 0, 0, 0};

    auto gi = [&](int k) { return esrc[start + (k < cnt ? k : cnt - 1)]; };
    auto idx4 = [&](int k) {
        int4 r; r.x = gi(k); r.y = gi(k + 1); r.z = gi(k + 2); r.w = gi(k + 3);
        return r;
    };
    auto issue = [&](int4 s, float4& ee, uint2& q0, uint2& q1, uint2& q2, uint2& q3) {
        ee.x = als[(size_t)s.x * 8 + h];
        ee.y = als[(size_t)s.y * 8 + h];
        ee.z = als[(size_t)s.z * 8 + h];
        ee.w = als[(size_t)s.w * 8 + h];
        q0 = *(const uint2*)&h3pb[(size_t)s.x * 256 + loff];
        q1 = *(const uint2*)&h3pb[(size_t)s.y * 256 + loff];
        q2 = *(const uint2*)&h3pb[(size_t)s.z * 256 + loff];
        q3 = *(const uint2*)&h3pb[(size_t)s.w * 256 + loff];
    };
    auto upedge = [&](float e, uint2 q, float& m, float& d, float4& a) {
        if (__any(e - m > RESCALE_THR)) {
            float nm = fmaxf(m, e), sc = __expf(m - nm);
            d *= sc;
            a.x *= sc; a.y *= sc; a.z *= sc; a.w *= sc;
            m = nm;
        }
        float ee = __expf(e - m);
        d += ee;
        a.x = fmaf(ee, bflo(q.x), a.x);
        a.y = fmaf(ee, bfhi(q.x), a.y);
        a.z = fmaf(ee, bflo(q.y), a.z);
        a.w = fmaf(ee, bfhi(q.y), a.w);
    };
    auto lrelu = [&](float e, int k) {
        e += aldv;
        e = (e > 0.f) ? e : NEG_SLOPE * e;
        return (k < cnt) ? e : -1e30f;
    };
    auto upd = [&](int base, float4 ee, uint2 q0, uint2 q1, uint2 q2, uint2 q3) {
        if (base >= cnt) return;
        upedge(lrelu(ee.x, base + 0), q0, mA, dA, accA);
        upedge(lrelu(ee.y, base + 1), q1, mA, dA, accA);
        upedge(lrelu(ee.z, base + 2), q2, mB, dB, accB);
        upedge(lrelu(ee.w, base + 3), q3, mB, dB, accB);
    };

    int4 i0 = idx4(0), i1 = idx4(4);
    float4 eC, eD;
    uint2 q0C, q1C, q2C, q3C, q0D, q1D, q2D, q3D;
    issue(i0, eC, q0C, q1C, q2C, q3C);
    int nb = (cnt + 3) >> 2;
    for (int b = 0; b < nb; b += 2) {
        i0 = idx4((b + 2) * 4);
        issue(i1, eD, q0D, q1D, q2D, q3D);
        upd(b * 4, eC, q0C, q1C, q2C, q3C);
        i1 = idx4((b + 3) * 4);
        issue(i0, eC, q0C, q1C, q2C, q3C);
        upd((b + 1) * 4, eD, q0D, q1D, q2D, q3D);
    }

    float mm = fmaxf(mA, mB);
    float sA = __expf(mA - mm), sB = __expf(mB - mm);
    float den = dA * sA + dB * sB;
    float inv = 1.f / (den + 1e-16f);
    float4 v;
    v.x = (accA.x * sA + accB.x * sB) * inv;
    v.y = (accA.y * sA + accB.y * sB) * inv;
    v.z = (accA.z * sA + accB.z * sB) * inv;
    v.w = (accA.w * sA + accB.w * sB) * inv;

    // head-mean: same class quad lives at lanes c8, 8+c8, ..., 56+c8
#pragma unroll
    for (int o = 8; o < 64; o <<= 1) {
        v.x += __shfl_xor(v.x, o, 64);
        v.y += __shfl_xor(v.y, o, 64);
        v.z += __shfl_xor(v.z, o, 64);
        v.w += __shfl_xor(v.w, o, 64);
    }
    int cq = c8 * 4;
    v.x = v.x * 0.125f + b3[cq + 0];
    v.y = v.y * 0.125f + b3[cq + 1];
    v.z = v.z * 0.125f + b3[cq + 2];
    v.w = v.w * 0.125f + b3[cq + 3];
    float mx = fmaxf(fmaxf(v.x, v.y), fmaxf(v.z, v.w));
#pragma unroll
    for (int o = 1; o < 8; o <<= 1) mx = fmaxf(mx, __shfl_xor(mx, o, 64));
    float ex = __expf(v.x - mx) + __expf(v.y - mx) + __expf(v.z - mx) + __expf(v.w - mx);
#pragma unroll
    for (int o = 1; o < 8; o <<= 1) ex += __shfl_xor(ex, o, 64);
    float lse = mx + __logf(ex);
    if (lane < 8) {
        float4 r4 = {v.x - lse, v.y - lse, v.z - lse, v.w - lse};
        *(float4*)&out[(size_t)node * 32 + cq] = r4;
    }
}

// ---------------- host launch ----------------
extern "C" void kernel_launch(void* const* d_in, const int* in_sizes, int n_in,
                              void* d_out, int out_size, void* d_ws, size_t ws_size,
                              hipStream_t stream)
{
    const float* x   = (const float*)d_in[0];
    const int*   ei  = (const int*)  d_in[1];
    const float* W1  = (const float*)d_in[2];
    const float* as1 = (const float*)d_in[3];
    const float* ad1 = (const float*)d_in[4];
    const float* b1  = (const float*)d_in[5];
    const float* W2  = (const float*)d_in[6];
    const float* as2 = (const float*)d_in[7];
    const float* ad2 = (const float*)d_in[8];
    const float* b2  = (const float*)d_in[9];
    const float* W3  = (const float*)d_in[10];
    const float* as3 = (const float*)d_in[11];
    const float* ad3 = (const float*)d_in[12];
    const float* b3  = (const float*)d_in[13];
    float* out = (float*)d_out;

    const int N = in_sizes[0] / DIM_IN;
    const int E = in_sizes[1] / 2;
    const int Etot = E + N;

    float* ws = (float*)d_ws;
    size_t o = 0;
    float* p2  = ws + o; o += (size_t)N * 64;                // x@W2a (f32)
    float* h1  = ws + o; o += (size_t)N * 64;                // layer-1 out (f32)
    ushort* hp1b  = (ushort*)(ws + o); o += (size_t)N * 32;  // x@W1 (bf16)
    ushort* h2pb  = (ushort*)(ws + o); o += (size_t)N * 32;  // h2pre (bf16)
    ushort* h2b   = (ushort*)(ws + o); o += (size_t)N * 32;  // layer-2 out (bf16)
    ushort* h3pb  = (ushort*)(ws + o); o += (size_t)N * 128; // h2@W3 (bf16)
    float* als = ws + o; o += (size_t)N * 8;
    float* ald = ws + o; o += (size_t)N * 8;
    float* wts = ws + o; o += 512;
    float* wtd = ws + o; o += 512;
    ushort* wpack  = (ushort*)(ws + o); o += 65536;          // 131072 ushorts
    ushort* w3pack = (ushort*)(ws + o); o += 8192;           // 16384 ushorts
    int* deg    = (int*)(ws + o); o += N;
    int* rowptr = (int*)(ws + o); o += N + 1;
    int* cursor = (int*)(ws + o); o += N;
    int* esrc   = (int*)(ws + o); o += Etot;
    if (o * 4 > ws_size) return;  // workspace too small -> visible failure

    const int TB = 256;

    pack_w<<<64, TB, 0, stream>>>(W1, W2, wpack);
    pack_w3<<<8, TB, 0, stream>>>(W3, w3pack);
    gemm1_mfma<<<(N + 63) / 64, TB, 0, stream>>>(x, wpack, hp1b, p2, N);

    hipMemsetAsync(deg, 0, (size_t)N * 4, stream);
    csr_hist<<<(Etot + TB - 1) / TB, TB, 0, stream>>>(ei, E, Etot, deg);
    csr_scan<<<1, 1024, 0, stream>>>(deg, rowptr, cursor, N);
    csr_fill<<<(Etot + TB - 1) / TB, TB, 0, stream>>>(ei, E, Etot, cursor, esrc);

    // ---- layer 1 ----
    attn_dots_b8<<<(N * 8 + TB - 1) / TB, TB, 0, stream>>>(hp1b, as1, ad1, als, ald, N * 8);
    gat_gather64<false><<<(N + 3) / 4, TB, 0, stream>>>(rowptr, esrc, als, ald, hp1b, b1, h1, nullptr, N);

    // h2pre = bf16(p2 + h1 @ W2[1000:1064])
    gemm_k64_n64_acc<<<(N + 15) / 16, TB, 0, stream>>>(h1, W2 + (size_t)DIM_IN * 64, p2, h2pb, N);

    // ---- layer 2 (bf16 in/out) ----
    attn_dots_b8<<<(N * 8 + TB - 1) / TB, TB, 0, stream>>>(h2pb, as2, ad2, als, ald, N * 8);
    gat_gather64<true><<<(N + 3) / 4, TB, 0, stream>>>(rowptr, esrc, als, ald, h2pb, b2, nullptr, h2b, N);

    // ---- layer 3 ----
    gemm3_mfma<<<(N + 15) / 16, TB, 0, stream>>>(h2b, w3pack, h3pb, N);
    make_wtilde<<<1, 512, 0, stream>>>(W3, as3, ad3, wts, wtd);
    attn_dots_w<<<(N * 8 + TB - 1) / TB, TB, 0, stream>>>(h2b, wts, wtd, als, ald, N * 8);
    gat_l3_final<<<(N + 3) / 4, TB, 0, stream>>>(rowptr, esrc, als, ald, h3pb, b3, out, N);
}